// Round 8
// baseline (137.124 us; speedup 1.0000x reference)
//
#include <hip/hip_runtime.h>

typedef unsigned short u16;
typedef short v8s __attribute__((ext_vector_type(8)));
typedef float v4f __attribute__((ext_vector_type(4)));

namespace {
constexpr int kC = 384;
constexpr int kN1 = 513;
constexpr int kH = 6;
constexpr int kBH = 48;      // B*H
constexpr int kRows = 4104;  // B*N1 tokens per half
constexpr int kRows2 = 8208; // B*M
constexpr int kPld = 576;    // Vt k-stride in bf16 elems (64*9)
constexpr int kTotX = 8208 * 384;  // x element count
}  // namespace

#if __has_builtin(__builtin_amdgcn_exp2f)
#define EXP2F(x) __builtin_amdgcn_exp2f(x)
#else
#define EXP2F(x) exp2f(x)
#endif

__device__ __forceinline__ u16 f2b(float f) {
  unsigned int u = __float_as_uint(f);
  u += 0x7fffu + ((u >> 16) & 1u);
  return (u16)(u >> 16);
}

__device__ __forceinline__ float b2f(u16 b) {
  return __uint_as_float(((unsigned)b) << 16);
}

__device__ __forceinline__ int gumbel_argmax(const float* __restrict__ w,
                                             const float* __restrict__ g) {
  float v0 = w[0] + g[0], v1 = w[1] + g[1], v2 = w[2] + g[2], v3 = w[3] + g[3];
  int j = 0;
  float m = v0;
  if (v1 > m) { m = v1; j = 1; }
  if (v2 > m) { m = v2; j = 2; }
  if (v3 > m) { m = v3; j = 3; }
  return j;
}

// ---- weights-only prep: select + transpose + convert 5 weights to bf16 [n][k]
// blocks >= 720 additionally convert x fp32->bf16 (coalesced stream).
__global__ __launch_bounds__(256) void prep_w(
    const float* __restrict__ Wq1, const float* __restrict__ Wq2,
    const float* __restrict__ Wk1, const float* __restrict__ Wk2,
    const float* __restrict__ Wv1, const float* __restrict__ Wv2,
    const float* __restrict__ Wo, const float* __restrict__ x,
    const float* __restrict__ wts, const float* __restrict__ gum,
    u16* __restrict__ Wqt, u16* __restrict__ Wkt, u16* __restrict__ Wv1t,
    u16* __restrict__ Wv2t, u16* __restrict__ Wot, u16* __restrict__ xb) {
  const int bx = blockIdx.x;
  if (bx >= 720) {  // ---- x convert: 4096 elems per block, 2 passes of 2048
    const int base = (bx - 720) * 4096 + (int)threadIdx.x * 8;
    for (int p = 0; p < 2; ++p) {
      const int idx = base + p * 2048;
      if (idx < kTotX) {
        const float4 f0 = *(const float4*)(x + idx);
        const float4 f1 = *(const float4*)(x + idx + 4);
        const v8s v = {(short)f2b(f0.x), (short)f2b(f0.y), (short)f2b(f0.z),
                       (short)f2b(f0.w), (short)f2b(f1.x), (short)f2b(f1.y),
                       (short)f2b(f1.z), (short)f2b(f1.w)};
        *(v8s*)(xb + idx) = v;
      }
    }
    return;
  }
  __shared__ float tb[32][33];
  const int z = bx / 144, rem = bx - z * 144;
  const int c0 = (rem % 12) * 32, r0 = (rem / 12) * 32;
  const int j = gumbel_argmax(wts, gum);
  const float* src;
  u16* dst;
  switch (z) {
    case 0: src = (j < 2) ? Wq1 : Wq2; dst = Wqt; break;
    case 1: src = (j == 0 || j == 2) ? Wk1 : Wk2; dst = Wkt; break;
    case 2: src = Wv1; dst = Wv1t; break;
    case 3: src = Wv2; dst = Wv2t; break;
    default: src = Wo; dst = Wot; break;
  }
  const int tx = threadIdx.x & 31, ty = threadIdx.x >> 5;
  for (int p = 0; p < 4; ++p)
    tb[ty + p * 8][tx] = src[(size_t)(r0 + ty + p * 8) * kC + c0 + tx];
  __syncthreads();
  for (int p = 0; p < 4; ++p)
    dst[(size_t)(c0 + ty + p * 8) * kC + r0 + tx] = f2b(tb[tx][ty + p * 8]);
}

// ---- fused QKV projections, bf16 MFMA. Double-buffered LDS: ONE barrier
// per k-tile; row pointers hoisted out of the k-loop (advance +64/iter);
// tail rows clamped (dup data, discarded at epilogue) instead of zero-fill.
__global__ __launch_bounds__(256) void qkv_mfma(
    const u16* __restrict__ xb, const u16* __restrict__ Wqt,
    const u16* __restrict__ Wkt, const u16* __restrict__ Wv1t,
    const u16* __restrict__ Wv2t, const float* __restrict__ bq1,
    const float* __restrict__ bq2, const float* __restrict__ bk1,
    const float* __restrict__ bk2, const float* __restrict__ bv1,
    const float* __restrict__ bv2, const float* __restrict__ wts,
    const float* __restrict__ gum, u16* __restrict__ Qb, u16* __restrict__ Kb,
    u16* __restrict__ Vt1, u16* __restrict__ Vt2) {
  const int bid = blockIdx.x;
  const int xcd = bid & 7;
  const int op = xcd >> 1;
  const int wu = (bid >> 3) * 2 + (xcd & 1);
  if (wu >= 99) return;
  const int mb33 = wu / 3, nb3 = wu - mb33 * 3;

  __shared__ __align__(16) u16 As[2][128][72];
  __shared__ __align__(16) u16 Bs[2][128][72];
  const int j = gumbel_argmax(wts, gum);
  const bool vmode = (op >= 2);
  const float* bias;
  int xoff;
  const u16* Wt;
  if (op == 0) {
    bias = (j < 2) ? bq1 : bq2; xoff = (j < 2) ? 0 : kN1; Wt = Wqt;
  } else if (op == 1) {
    const bool u1 = (j == 0 || j == 2);
    bias = u1 ? bk1 : bk2; xoff = u1 ? 0 : kN1; Wt = Wkt;
  } else if (op == 2) {
    bias = bv1; xoff = 0; Wt = Wv1t;
  } else {
    bias = bv2; xoff = kN1; Wt = Wv2t;
  }
  const int m0 = (vmode ? nb3 : mb33) * 128;
  const int n0 = (vmode ? mb33 : nb3) * 128;
  const int tid = threadIdx.x;
  const int lane = tid & 63, l16 = lane & 15, quad = lane >> 4;
  const int wv = tid >> 6, wr = wv >> 1, wc = wv & 1;
  const int sr = tid >> 2, sc = (tid & 3) * 16;

  v4f acc[4][4];
  const v4f z4 = {0.f, 0.f, 0.f, 0.f};
  for (int i = 0; i < 4; ++i)
    for (int n = 0; n < 4; ++n) acc[i][n] = z4;

  // ---- hoisted row pointers (k-loop advances them by 64) ----
  const u16 *pA0, *pA1, *pB0, *pB1;
  {
    auto xrow = [&](int t) -> const u16* {  // clamped token row pointer
      if (t >= kRows) t = kRows - 1;        // dup row: C rows/cols discarded
      const int bb = t / kN1, mm = t - bb * kN1;
      return xb + ((size_t)(bb * 1026 + xoff + mm)) * kC + sc;
    };
    if (!vmode) {
      pA0 = xrow(m0 + sr);
      pA1 = xrow(m0 + 64 + sr);
      pB0 = Wt + (size_t)(n0 + sr) * kC + sc;
      pB1 = Wt + (size_t)(n0 + 64 + sr) * kC + sc;
    } else {
      pA0 = Wt + (size_t)(m0 + sr) * kC + sc;
      pA1 = Wt + (size_t)(m0 + 64 + sr) * kC + sc;
      pB0 = xrow(n0 + sr);
      pB1 = xrow(n0 + 64 + sr);
    }
  }

  v8s a00 = *(const v8s*)pA0, a01 = *(const v8s*)(pA0 + 8);
  v8s a10 = *(const v8s*)pA1, a11 = *(const v8s*)(pA1 + 8);
  v8s b00 = *(const v8s*)pB0, b01 = *(const v8s*)(pB0 + 8);
  v8s b10 = *(const v8s*)pB1, b11 = *(const v8s*)(pB1 + 8);
  *(v8s*)&As[0][sr][sc] = a00;
  *(v8s*)&As[0][sr][sc + 8] = a01;
  *(v8s*)&As[0][64 + sr][sc] = a10;
  *(v8s*)&As[0][64 + sr][sc + 8] = a11;
  *(v8s*)&Bs[0][sr][sc] = b00;
  *(v8s*)&Bs[0][sr][sc + 8] = b01;
  *(v8s*)&Bs[0][64 + sr][sc] = b10;
  *(v8s*)&Bs[0][64 + sr][sc + 8] = b11;
  __syncthreads();

  for (int it = 0; it < 6; ++it) {
    const int cur = it & 1;
    if (it < 5) {  // issue next tile's loads; latency hides under MFMA
      pA0 += 64; pA1 += 64; pB0 += 64; pB1 += 64;
      a00 = *(const v8s*)pA0; a01 = *(const v8s*)(pA0 + 8);
      a10 = *(const v8s*)pA1; a11 = *(const v8s*)(pA1 + 8);
      b00 = *(const v8s*)pB0; b01 = *(const v8s*)(pB0 + 8);
      b10 = *(const v8s*)pB1; b11 = *(const v8s*)(pB1 + 8);
    }
    for (int ks = 0; ks < 2; ++ks) {
      v8s af[4], bfr[4];
      for (int i = 0; i < 4; ++i)
        af[i] = *(const v8s*)&As[cur][wr * 64 + i * 16 + l16][ks * 32 + quad * 8];
      for (int n = 0; n < 4; ++n)
        bfr[n] = *(const v8s*)&Bs[cur][wc * 64 + n * 16 + l16][ks * 32 + quad * 8];
      for (int i = 0; i < 4; ++i)
        for (int n = 0; n < 4; ++n)
          acc[i][n] = __builtin_amdgcn_mfma_f32_16x16x32_bf16(af[i], bfr[n],
                                                              acc[i][n], 0, 0, 0);
    }
    if (it < 5) {  // stage next tile into the other buffer; ONE barrier/iter
      *(v8s*)&As[cur ^ 1][sr][sc] = a00;
      *(v8s*)&As[cur ^ 1][sr][sc + 8] = a01;
      *(v8s*)&As[cur ^ 1][64 + sr][sc] = a10;
      *(v8s*)&As[cur ^ 1][64 + sr][sc + 8] = a11;
      *(v8s*)&Bs[cur ^ 1][sr][sc] = b00;
      *(v8s*)&Bs[cur ^ 1][sr][sc + 8] = b01;
      *(v8s*)&Bs[cur ^ 1][64 + sr][sc] = b10;
      *(v8s*)&Bs[cur ^ 1][64 + sr][sc + 8] = b11;
      __syncthreads();
    }
  }

  if (!vmode) {
    u16* outp = (op == 0) ? Qb : Kb;
    // 0.125 (d^-0.5) * log2(e) folded so attn can use exp2 directly
    const float osc = (op == 0) ? 0.18033688011112042f : 1.0f;
    float bv4[4];
    for (int nt = 0; nt < 4; ++nt) bv4[nt] = bias[n0 + wc * 64 + nt * 16 + l16];
    for (int i = 0; i < 4; ++i) {
      const int rowb = m0 + wr * 64 + i * 16 + quad * 4;
      for (int r = 0; r < 4; ++r) {
        const int row = rowb + r;
        if (row >= kRows) continue;
        for (int nt = 0; nt < 4; ++nt) {
          const int col = n0 + wc * 64 + nt * 16 + l16;
          outp[(size_t)row * kC + col] = f2b((acc[i][nt][r] + bv4[nt]) * osc);
        }
      }
    }
  } else {
    u16* Vt = (op == 2) ? Vt1 : Vt2;
    for (int nt = 0; nt < 4; ++nt) {
      const int t = n0 + wc * 64 + nt * 16 + l16;  // token
      if (t >= kRows) continue;
      const int bb = t / kN1, mm = t - bb * kN1;
      for (int i = 0; i < 4; ++i) {
        const int colb = m0 + wr * 64 + i * 16 + quad * 4;
        for (int r = 0; r < 4; ++r) {
          const int col = colb + r;
          const int hh = col >> 6, d = col & 63;
          Vt[((size_t)(bb * kH + hh) * 64 + d) * kPld + mm] =
              f2b(acc[i][nt][r] + bias[col]);
        }
      }
    }
  }
}

// ---- fused flash attention: 8 FULL k-tiles + exact k=512 epilogue.
// Double-buffered Ks/Vs: ONE barrier per k-tile (loads issued at iter start,
// reg->LDS writes after compute). Ps is wave-private (no barrier needed).
// Blocks with q0==512 take a slim GEVM path. setprio(1) wraps MFMA clusters.
__global__ __launch_bounds__(256) void attn_fused(const u16* __restrict__ Qb,
                                                  const u16* __restrict__ Kb,
                                                  const u16* __restrict__ Vt1,
                                                  const u16* __restrict__ Vt2,
                                                  u16* __restrict__ PRE) {
  __shared__ __align__(16) u16 Ks[2][64][72];
  __shared__ __align__(16) u16 Vs[2][128][72];
  __shared__ __align__(16) u16 Ps[4][16][72];
  const int bid = blockIdx.x;
  const int xcd = bid & 7;
  const int t6 = bid >> 3;           // 0..53
  const int bh = xcd * 6 + (t6 % 6); // 0..47
  const int q0 = (t6 / 6) * 64;      // 9 q-tiles
  const int b = bh / kH, hh = bh - b * kH;
  const int tid = threadIdx.x;
  const int w = tid >> 6, lane = tid & 63, l16 = lane & 15, quad = lane >> 4;

  if (q0 == 512) {  // ---- slim path: only q-row 512 is valid ----
    float* Pp = (float*)&Ks[0][0][0];    // 513 floats
    float* Rd = (float*)&Vs[0][0][0];    // 256 floats
    float* wred = (float*)&Ps[0][0][0];  // 4 floats
    v8s q8[8];
    const u16* qs = Qb + ((size_t)(b * kN1 + 512)) * kC + hh * 64;
    for (int c = 0; c < 8; ++c) q8[c] = *(const v8s*)(qs + c * 8);
    for (int k = tid; k < kN1; k += 256) {
      const u16* kr = Kb + ((size_t)(b * kN1 + k)) * kC + hh * 64;
      float s = 0.f;
      for (int c = 0; c < 8; ++c) {
        const v8s kv = *(const v8s*)(kr + c * 8);
        for (int jj = 0; jj < 8; ++jj)
          s += b2f((u16)q8[c][jj]) * b2f((u16)kv[jj]);
      }
      Pp[k] = EXP2F(s);
    }
    __syncthreads();
    float part = 0.f;
    for (int k = tid; k < kN1; k += 256) part += Pp[k];
    for (int o = 1; o < 64; o <<= 1) part += __shfl_xor(part, o);
    if (lane == 0) wred[w] = part;
    __syncthreads();
    const float rinv = 1.f / (wred[0] + wred[1] + wred[2] + wred[3]);
    const int d = tid & 127, half = tid >> 7;
    const u16* vrow = (d < 64) ? (Vt1 + ((size_t)bh * 64 + d) * kPld)
                               : (Vt2 + ((size_t)bh * 64 + (d - 64)) * kPld);
    float acc = 0.f;
    const int kb0 = half * 256;
    for (int k8 = 0; k8 < 256; k8 += 8) {
      const v8s vv = *(const v8s*)(vrow + kb0 + k8);
      for (int jj = 0; jj < 8; ++jj)
        acc += Pp[kb0 + k8 + jj] * b2f((u16)vv[jj]);
    }
    if (half) acc += Pp[512] * b2f(vrow[512]);
    Rd[tid] = acc;
    __syncthreads();
    if (tid < 128) {
      const float o = (Rd[tid] + Rd[tid + 128]) * rinv;
      const int row = b * 1026 + ((d < 64) ? 512 : (kN1 + 512));
      const int col = hh * 64 + (d & 63);
      PRE[(size_t)row * kC + col] = f2b(o);
    }
    return;
  }

  v8s aq0, aq1;
  {  // Q fragments straight from global (each wave reads only its 16 rows)
    const int qr = q0 + w * 16 + l16;  // q0 <= 448 here: qr <= 511
    const u16* qs = Qb + ((size_t)(b * kN1 + qr)) * kC + hh * 64 + quad * 8;
    aq0 = *(const v8s*)qs;
    aq1 = *(const v8s*)(qs + 32);
  }
  const int ksr = tid >> 2, ksc = (tid & 3) * 16;
  const int vd = tid >> 1, vc = (tid & 1) * 32;
  const u16* kbase = Kb + (size_t)b * kN1 * kC + hh * 64 + ksc;
  const u16* vbase = ((vd < 64) ? (Vt1 + ((size_t)bh * 64 + vd) * kPld)
                                : (Vt2 + ((size_t)bh * 64 + (vd - 64)) * kPld)) +
                     vc;
  v8s kr0, kr1, vr0, vr1, vr2, vr3;
  {  // load tile 0 and stage into buf 0
    const u16* s = kbase + (size_t)ksr * kC;
    kr0 = *(const v8s*)s;
    kr1 = *(const v8s*)(s + 8);
    vr0 = *(const v8s*)(vbase);
    vr1 = *(const v8s*)(vbase + 8);
    vr2 = *(const v8s*)(vbase + 16);
    vr3 = *(const v8s*)(vbase + 24);
    *(v8s*)&Ks[0][ksr][ksc] = kr0;
    *(v8s*)&Ks[0][ksr][ksc + 8] = kr1;
    *(v8s*)&Vs[0][vd][vc] = vr0;
    *(v8s*)&Vs[0][vd][vc + 8] = vr1;
    *(v8s*)&Vs[0][vd][vc + 16] = vr2;
    *(v8s*)&Vs[0][vd][vc + 24] = vr3;
  }
  __syncthreads();

  float lsum[4] = {0.f, 0.f, 0.f, 0.f};
  v4f Oacc[8];
  const v4f z4 = {0.f, 0.f, 0.f, 0.f};
  for (int n = 0; n < 8; ++n) Oacc[n] = z4;

  for (int kt = 0; kt < 8; ++kt) {
    const int cur = kt & 1;
    if (kt < 7) {  // issue loads for kt+1 at iter start; hide under compute
      const int k0n = kt * 64 + 64;
      const u16* s = kbase + (size_t)(k0n + ksr) * kC;  // rows <= 511
      kr0 = *(const v8s*)s;
      kr1 = *(const v8s*)(s + 8);
      const u16* t = vbase + k0n;
      vr0 = *(const v8s*)t;
      vr1 = *(const v8s*)(t + 8);
      vr2 = *(const v8s*)(t + 16);
      vr3 = *(const v8s*)(t + 24);
    }
    v4f sacc[4];
    for (int nt = 0; nt < 4; ++nt) sacc[nt] = z4;
    __builtin_amdgcn_s_setprio(1);
    for (int nt = 0; nt < 4; ++nt) {
      const v8s bk0 = *(const v8s*)&Ks[cur][nt * 16 + l16][quad * 8];
      sacc[nt] = __builtin_amdgcn_mfma_f32_16x16x32_bf16(aq0, bk0, sacc[nt], 0, 0, 0);
      const v8s bk1 = *(const v8s*)&Ks[cur][nt * 16 + l16][32 + quad * 8];
      sacc[nt] = __builtin_amdgcn_mfma_f32_16x16x32_bf16(aq1, bk1, sacc[nt], 0, 0, 0);
    }
    __builtin_amdgcn_s_setprio(0);
    for (int r = 0; r < 4; ++r) {  // all 8 tiles fully valid: no masking
      float ps = 0.f;
      for (int nt = 0; nt < 4; ++nt) {
        const float p = EXP2F(sacc[nt][r]);
        ps += p;
        Ps[w][quad * 4 + r][nt * 16 + l16] = f2b(p);
      }
      lsum[r] += ps;
    }
    __builtin_amdgcn_s_setprio(1);
    for (int kc = 0; kc < 2; ++kc) {
      const v8s ap = *(const v8s*)&Ps[w][l16][kc * 32 + quad * 8];
      for (int n = 0; n < 8; ++n) {
        const v8s bv = *(const v8s*)&Vs[cur][n * 16 + l16][kc * 32 + quad * 8];
        Oacc[n] = __builtin_amdgcn_mfma_f32_16x16x32_bf16(ap, bv, Oacc[n], 0, 0, 0);
      }
    }
    __builtin_amdgcn_s_setprio(0);
    if (kt < 7) {  // stage kt+1 into the other buffer; ONE barrier per iter
      *(v8s*)&Ks[cur ^ 1][ksr][ksc] = kr0;
      *(v8s*)&Ks[cur ^ 1][ksr][ksc + 8] = kr1;
      *(v8s*)&Vs[cur ^ 1][vd][vc] = vr0;
      *(v8s*)&Vs[cur ^ 1][vd][vc + 8] = vr1;
      *(v8s*)&Vs[cur ^ 1][vd][vc + 16] = vr2;
      *(v8s*)&Vs[cur ^ 1][vd][vc + 24] = vr3;
      __syncthreads();
    }
  }

  {  // ---- exact k = 512 column ----
    const u16* k512 = Kb + ((size_t)(b * kN1 + 512)) * kC + hh * 64 + quad * 8;
    const v8s kv0 = *(const v8s*)k512;
    const v8s kv1 = *(const v8s*)(k512 + 32);
    float part = 0.f;
    for (int jj = 0; jj < 8; ++jj) {
      part += b2f((u16)aq0[jj]) * b2f((u16)kv0[jj]);
      part += b2f((u16)aq1[jj]) * b2f((u16)kv1[jj]);
    }
    part += __shfl_xor(part, 16);
    part += __shfl_xor(part, 32);  // all lanes: full dot for row w*16+l16
    const float p512 = EXP2F(part);
    float pb[4];
    for (int r = 0; r < 4; ++r) pb[r] = __shfl(p512, quad * 4 + r);
    // each of the 16 l16-lanes adds pb; the final xor-reduce over l16 sums
    // them 16x -> scale by 1/16 so p512 is counted exactly once per row.
    for (int r = 0; r < 4; ++r) lsum[r] += pb[r] * 0.0625f;
    for (int n = 0; n < 8; ++n) {
      const int d = (n & 3) * 16 + l16;
      const u16* vp = (n < 4) ? (Vt1 + ((size_t)bh * 64 + d) * kPld + 512)
                              : (Vt2 + ((size_t)bh * 64 + d) * kPld + 512);
      const float vv = b2f(*vp);
      for (int r = 0; r < 4; ++r) Oacc[n][r] += pb[r] * vv;
    }
  }

  float rinv[4];
  for (int r = 0; r < 4; ++r) {
    float s = lsum[r];
    for (int o = 1; o <= 8; o <<= 1) s += __shfl_xor(s, o);
    rinv[r] = 1.f / s;
  }
  for (int n = 0; n < 8; ++n) {
    const int col = hh * 64 + (n & 3) * 16 + l16;
    const int rbase = b * 1026 + ((n < 4) ? 0 : kN1);
    for (int r = 0; r < 4; ++r) {
      const int q = q0 + w * 16 + quad * 4 + r;
      PRE[(size_t)(rbase + q) * kC + col] = f2b(Oacc[n][r] * rinv[r]);
    }
  }
}

// ---- OUT = PRE @ Wo + bo (fp32 out). 128x64 tiles -> grid (65,6)=390
// blocks (~1.5/CU; old (65,3)=195 left 24% of CUs idle). Double-buffered
// LDS, ONE barrier per k-tile (6 tiles of 64); hoisted row pointers;
// clamped tail rows (discarded at write). Wave tile 64x32: acc[4][2].
__global__ __launch_bounds__(256) void out_mfma(const u16* __restrict__ PRE,
                                                const u16* __restrict__ Wot,
                                                const float* __restrict__ bo,
                                                float* __restrict__ OUT) {
  __shared__ __align__(16) u16 As[2][128][72];
  __shared__ __align__(16) u16 Bs[2][64][72];
  const int m0 = blockIdx.x * 128, n0 = blockIdx.y * 64;
  const int tid = threadIdx.x;
  const int lane = tid & 63, l16 = lane & 15, quad = lane >> 4;
  const int wv = tid >> 6, wr = wv >> 1, wc = wv & 1;
  const int sr = tid >> 2, sc = (tid & 3) * 16;
  v4f acc[4][2];
  const v4f z4 = {0.f, 0.f, 0.f, 0.f};
  for (int i = 0; i < 4; ++i)
    for (int n = 0; n < 2; ++n) acc[i][n] = z4;

  int rA0 = m0 + sr;       if (rA0 >= kRows2) rA0 = kRows2 - 1;
  int rA1 = m0 + 64 + sr;  if (rA1 >= kRows2) rA1 = kRows2 - 1;
  const u16* pA0 = PRE + (size_t)rA0 * kC + sc;
  const u16* pA1 = PRE + (size_t)rA1 * kC + sc;
  const u16* pB0 = Wot + (size_t)(n0 + sr) * kC + sc;  // 64 B rows

  v8s a00 = *(const v8s*)pA0, a01 = *(const v8s*)(pA0 + 8);
  v8s a10 = *(const v8s*)pA1, a11 = *(const v8s*)(pA1 + 8);
  v8s b00 = *(const v8s*)pB0, b01 = *(const v8s*)(pB0 + 8);
  *(v8s*)&As[0][sr][sc] = a00;
  *(v8s*)&As[0][sr][sc + 8] = a01;
  *(v8s*)&As[0][64 + sr][sc] = a10;
  *(v8s*)&As[0][64 + sr][sc + 8] = a11;
  *(v8s*)&Bs[0][sr][sc] = b00;
  *(v8s*)&Bs[0][sr][sc + 8] = b01;
  __syncthreads();

  for (int it = 0; it < 6; ++it) {
    const int cur = it & 1;
    if (it < 5) {
      pA0 += 64; pA1 += 64; pB0 += 64;
      a00 = *(const v8s*)pA0; a01 = *(const v8s*)(pA0 + 8);
      a10 = *(const v8s*)pA1; a11 = *(const v8s*)(pA1 + 8);
      b00 = *(const v8s*)pB0; b01 = *(const v8s*)(pB0 + 8);
    }
    for (int ks = 0; ks < 2; ++ks) {
      v8s af[4], bfr[2];
      for (int i = 0; i < 4; ++i)
        af[i] = *(const v8s*)&As[cur][wr * 64 + i * 16 + l16][ks * 32 + quad * 8];
      for (int n = 0; n < 2; ++n)
        bfr[n] = *(const v8s*)&Bs[cur][wc * 32 + n * 16 + l16][ks * 32 + quad * 8];
      for (int i = 0; i < 4; ++i)
        for (int n = 0; n < 2; ++n)
          acc[i][n] = __builtin_amdgcn_mfma_f32_16x16x32_bf16(af[i], bfr[n],
                                                              acc[i][n], 0, 0, 0);
    }
    if (it < 5) {
      *(v8s*)&As[cur ^ 1][sr][sc] = a00;
      *(v8s*)&As[cur ^ 1][sr][sc + 8] = a01;
      *(v8s*)&As[cur ^ 1][64 + sr][sc] = a10;
      *(v8s*)&As[cur ^ 1][64 + sr][sc + 8] = a11;
      *(v8s*)&Bs[cur ^ 1][sr][sc] = b00;
      *(v8s*)&Bs[cur ^ 1][sr][sc + 8] = b01;
      __syncthreads();
    }
  }
  float bv2[2];
  for (int nt = 0; nt < 2; ++nt) bv2[nt] = bo[n0 + wc * 32 + nt * 16 + l16];
  for (int i = 0; i < 4; ++i) {
    const int rowb = m0 + wr * 64 + i * 16 + quad * 4;
    for (int r = 0; r < 4; ++r) {
      const int row = rowb + r;
      if (row >= kRows2) continue;
      for (int nt = 0; nt < 2; ++nt) {
        const int col = n0 + wc * 32 + nt * 16 + l16;
        OUT[(size_t)row * kC + col] = acc[i][nt][r] + bv2[nt];
      }
    }
  }
}

extern "C" void kernel_launch(void* const* d_in, const int* in_sizes, int n_in,
                              void* d_out, int out_size, void* d_ws,
                              size_t ws_size, hipStream_t stream) {
  const float* x = (const float*)d_in[0];
  const float* Wq1 = (const float*)d_in[1];
  const float* bq1 = (const float*)d_in[2];
  const float* Wq2 = (const float*)d_in[3];
  const float* bq2 = (const float*)d_in[4];
  const float* Wk1 = (const float*)d_in[5];
  const float* bk1 = (const float*)d_in[6];
  const float* Wk2 = (const float*)d_in[7];
  const float* bk2 = (const float*)d_in[8];
  const float* Wv1 = (const float*)d_in[9];
  const float* bv1 = (const float*)d_in[10];
  const float* Wv2 = (const float*)d_in[11];
  const float* bv2 = (const float*)d_in[12];
  const float* Wo = (const float*)d_in[13];
  const float* bo = (const float*)d_in[14];
  const float* wts = (const float*)d_in[15];
  const float* gum = (const float*)d_in[16];
  (void)Wo;

  u16* Wqt = (u16*)d_ws;                         // 147456 elems each
  u16* Wkt = Wqt + 147456;
  u16* Wv1t = Wkt + 147456;
  u16* Wv2t = Wv1t + 147456;
  u16* Wot = Wv2t + 147456;
  u16* Qb = Wot + 147456;                        // 4104*384
  u16* Kb = Qb + (size_t)kRows * kC;             // 4104*384
  u16* Vt1 = Kb + (size_t)kRows * kC;            // 48*64*576
  u16* Vt2 = Vt1 + (size_t)kBH * 64 * kPld;      // 48*64*576
  u16* PRE = Vt2 + (size_t)kBH * 64 * kPld;      // 8208*384
  u16* XB = PRE + (size_t)kRows2 * kC;           // 8208*384 bf16 x

  prep_w<<<dim3(1490), 256, 0, stream>>>(Wq1, Wq2, Wk1, Wk2, Wv1, Wv2, Wo, x,
                                         wts, gum, Wqt, Wkt, Wv1t, Wv2t, Wot,
                                         XB);
  qkv_mfma<<<dim3(400), 256, 0, stream>>>(
      XB, Wqt, Wkt, Wv1t, Wv2t, bq1, bq2, bk1, bk2, bv1, bv2, wts, gum, Qb, Kb,
      Vt1, Vt2);
  attn_fused<<<dim3(432), 256, 0, stream>>>(Qb, Kb, Vt1, Vt2, PRE);
  out_mfma<<<dim3(65, 6), 256, 0, stream>>>(PRE, Wot, bo, (float*)d_out);
}

// Round 9
// 135.039 us; speedup vs baseline: 1.0154x; 1.0154x over previous
//
#include <hip/hip_runtime.h>

typedef unsigned short u16;
typedef short v8s __attribute__((ext_vector_type(8)));
typedef float v4f __attribute__((ext_vector_type(4)));

namespace {
constexpr int kC = 384;
constexpr int kN1 = 513;
constexpr int kH = 6;
constexpr int kBH = 48;      // B*H
constexpr int kRows = 4104;  // B*N1 tokens per half
constexpr int kRows2 = 8208; // B*M
constexpr int kPld = 576;    // Vt k-stride in bf16 elems (64*9)
constexpr int kTotX = 8208 * 384;  // x element count
}  // namespace

#if __has_builtin(__builtin_amdgcn_exp2f)
#define EXP2F(x) __builtin_amdgcn_exp2f(x)
#else
#define EXP2F(x) exp2f(x)
#endif

__device__ __forceinline__ u16 f2b(float f) {
  unsigned int u = __float_as_uint(f);
  u += 0x7fffu + ((u >> 16) & 1u);
  return (u16)(u >> 16);
}

__device__ __forceinline__ float b2f(u16 b) {
  return __uint_as_float(((unsigned)b) << 16);
}

__device__ __forceinline__ int gumbel_argmax(const float* __restrict__ w,
                                             const float* __restrict__ g) {
  float v0 = w[0] + g[0], v1 = w[1] + g[1], v2 = w[2] + g[2], v3 = w[3] + g[3];
  int j = 0;
  float m = v0;
  if (v1 > m) { m = v1; j = 1; }
  if (v2 > m) { m = v2; j = 2; }
  if (v3 > m) { m = v3; j = 3; }
  return j;
}

// ---- weights-only prep: select + transpose + convert 5 weights to bf16 [n][k]
// blocks >= 720 additionally convert x fp32->bf16 (coalesced stream).
__global__ __launch_bounds__(256) void prep_w(
    const float* __restrict__ Wq1, const float* __restrict__ Wq2,
    const float* __restrict__ Wk1, const float* __restrict__ Wk2,
    const float* __restrict__ Wv1, const float* __restrict__ Wv2,
    const float* __restrict__ Wo, const float* __restrict__ x,
    const float* __restrict__ wts, const float* __restrict__ gum,
    u16* __restrict__ Wqt, u16* __restrict__ Wkt, u16* __restrict__ Wv1t,
    u16* __restrict__ Wv2t, u16* __restrict__ Wot, u16* __restrict__ xb) {
  const int bx = blockIdx.x;
  if (bx >= 720) {  // ---- x convert: 4096 elems per block, 2 passes of 2048
    const int base = (bx - 720) * 4096 + (int)threadIdx.x * 8;
    for (int p = 0; p < 2; ++p) {
      const int idx = base + p * 2048;
      if (idx < kTotX) {
        const float4 f0 = *(const float4*)(x + idx);
        const float4 f1 = *(const float4*)(x + idx + 4);
        const v8s v = {(short)f2b(f0.x), (short)f2b(f0.y), (short)f2b(f0.z),
                       (short)f2b(f0.w), (short)f2b(f1.x), (short)f2b(f1.y),
                       (short)f2b(f1.z), (short)f2b(f1.w)};
        *(v8s*)(xb + idx) = v;
      }
    }
    return;
  }
  __shared__ float tb[32][33];
  const int z = bx / 144, rem = bx - z * 144;
  const int c0 = (rem % 12) * 32, r0 = (rem / 12) * 32;
  const int j = gumbel_argmax(wts, gum);
  const float* src;
  u16* dst;
  switch (z) {
    case 0: src = (j < 2) ? Wq1 : Wq2; dst = Wqt; break;
    case 1: src = (j == 0 || j == 2) ? Wk1 : Wk2; dst = Wkt; break;
    case 2: src = Wv1; dst = Wv1t; break;
    case 3: src = Wv2; dst = Wv2t; break;
    default: src = Wo; dst = Wot; break;
  }
  const int tx = threadIdx.x & 31, ty = threadIdx.x >> 5;
  for (int p = 0; p < 4; ++p)
    tb[ty + p * 8][tx] = src[(size_t)(r0 + ty + p * 8) * kC + c0 + tx];
  __syncthreads();
  for (int p = 0; p < 4; ++p)
    dst[(size_t)(c0 + ty + p * 8) * kC + r0 + tx] = f2b(tb[tx][ty + p * 8]);
}

// ---- fused QKV projections, bf16 MFMA. Double-buffered LDS: ONE barrier
// per k-tile; row pointers hoisted out of the k-loop (advance +64/iter);
// tail rows clamped (dup data, discarded at epilogue) instead of zero-fill.
__global__ __launch_bounds__(256) void qkv_mfma(
    const u16* __restrict__ xb, const u16* __restrict__ Wqt,
    const u16* __restrict__ Wkt, const u16* __restrict__ Wv1t,
    const u16* __restrict__ Wv2t, const float* __restrict__ bq1,
    const float* __restrict__ bq2, const float* __restrict__ bk1,
    const float* __restrict__ bk2, const float* __restrict__ bv1,
    const float* __restrict__ bv2, const float* __restrict__ wts,
    const float* __restrict__ gum, u16* __restrict__ Qb, u16* __restrict__ Kb,
    u16* __restrict__ Vt1, u16* __restrict__ Vt2) {
  const int bid = blockIdx.x;
  const int xcd = bid & 7;
  const int op = xcd >> 1;
  const int wu = (bid >> 3) * 2 + (xcd & 1);
  if (wu >= 99) return;
  const int mb33 = wu / 3, nb3 = wu - mb33 * 3;

  __shared__ __align__(16) u16 As[2][128][72];
  __shared__ __align__(16) u16 Bs[2][128][72];
  const int j = gumbel_argmax(wts, gum);
  const bool vmode = (op >= 2);
  const float* bias;
  int xoff;
  const u16* Wt;
  if (op == 0) {
    bias = (j < 2) ? bq1 : bq2; xoff = (j < 2) ? 0 : kN1; Wt = Wqt;
  } else if (op == 1) {
    const bool u1 = (j == 0 || j == 2);
    bias = u1 ? bk1 : bk2; xoff = u1 ? 0 : kN1; Wt = Wkt;
  } else if (op == 2) {
    bias = bv1; xoff = 0; Wt = Wv1t;
  } else {
    bias = bv2; xoff = kN1; Wt = Wv2t;
  }
  const int m0 = (vmode ? nb3 : mb33) * 128;
  const int n0 = (vmode ? mb33 : nb3) * 128;
  const int tid = threadIdx.x;
  const int lane = tid & 63, l16 = lane & 15, quad = lane >> 4;
  const int wv = tid >> 6, wr = wv >> 1, wc = wv & 1;
  const int sr = tid >> 2, sc = (tid & 3) * 16;

  v4f acc[4][4];
  const v4f z4 = {0.f, 0.f, 0.f, 0.f};
  for (int i = 0; i < 4; ++i)
    for (int n = 0; n < 4; ++n) acc[i][n] = z4;

  // ---- hoisted row pointers (k-loop advances them by 64) ----
  const u16 *pA0, *pA1, *pB0, *pB1;
  {
    auto xrow = [&](int t) -> const u16* {  // clamped token row pointer
      if (t >= kRows) t = kRows - 1;        // dup row: C rows/cols discarded
      const int bb = t / kN1, mm = t - bb * kN1;
      return xb + ((size_t)(bb * 1026 + xoff + mm)) * kC + sc;
    };
    if (!vmode) {
      pA0 = xrow(m0 + sr);
      pA1 = xrow(m0 + 64 + sr);
      pB0 = Wt + (size_t)(n0 + sr) * kC + sc;
      pB1 = Wt + (size_t)(n0 + 64 + sr) * kC + sc;
    } else {
      pA0 = Wt + (size_t)(m0 + sr) * kC + sc;
      pA1 = Wt + (size_t)(m0 + 64 + sr) * kC + sc;
      pB0 = xrow(n0 + sr);
      pB1 = xrow(n0 + 64 + sr);
    }
  }

  v8s a00 = *(const v8s*)pA0, a01 = *(const v8s*)(pA0 + 8);
  v8s a10 = *(const v8s*)pA1, a11 = *(const v8s*)(pA1 + 8);
  v8s b00 = *(const v8s*)pB0, b01 = *(const v8s*)(pB0 + 8);
  v8s b10 = *(const v8s*)pB1, b11 = *(const v8s*)(pB1 + 8);
  *(v8s*)&As[0][sr][sc] = a00;
  *(v8s*)&As[0][sr][sc + 8] = a01;
  *(v8s*)&As[0][64 + sr][sc] = a10;
  *(v8s*)&As[0][64 + sr][sc + 8] = a11;
  *(v8s*)&Bs[0][sr][sc] = b00;
  *(v8s*)&Bs[0][sr][sc + 8] = b01;
  *(v8s*)&Bs[0][64 + sr][sc] = b10;
  *(v8s*)&Bs[0][64 + sr][sc + 8] = b11;
  __syncthreads();

  for (int it = 0; it < 6; ++it) {
    const int cur = it & 1;
    if (it < 5) {  // issue next tile's loads; latency hides under MFMA
      pA0 += 64; pA1 += 64; pB0 += 64; pB1 += 64;
      a00 = *(const v8s*)pA0; a01 = *(const v8s*)(pA0 + 8);
      a10 = *(const v8s*)pA1; a11 = *(const v8s*)(pA1 + 8);
      b00 = *(const v8s*)pB0; b01 = *(const v8s*)(pB0 + 8);
      b10 = *(const v8s*)pB1; b11 = *(const v8s*)(pB1 + 8);
    }
    for (int ks = 0; ks < 2; ++ks) {
      v8s af[4], bfr[4];
      for (int i = 0; i < 4; ++i)
        af[i] = *(const v8s*)&As[cur][wr * 64 + i * 16 + l16][ks * 32 + quad * 8];
      for (int n = 0; n < 4; ++n)
        bfr[n] = *(const v8s*)&Bs[cur][wc * 64 + n * 16 + l16][ks * 32 + quad * 8];
      for (int i = 0; i < 4; ++i)
        for (int n = 0; n < 4; ++n)
          acc[i][n] = __builtin_amdgcn_mfma_f32_16x16x32_bf16(af[i], bfr[n],
                                                              acc[i][n], 0, 0, 0);
    }
    if (it < 5) {  // stage next tile into the other buffer; ONE barrier/iter
      *(v8s*)&As[cur ^ 1][sr][sc] = a00;
      *(v8s*)&As[cur ^ 1][sr][sc + 8] = a01;
      *(v8s*)&As[cur ^ 1][64 + sr][sc] = a10;
      *(v8s*)&As[cur ^ 1][64 + sr][sc + 8] = a11;
      *(v8s*)&Bs[cur ^ 1][sr][sc] = b00;
      *(v8s*)&Bs[cur ^ 1][sr][sc + 8] = b01;
      *(v8s*)&Bs[cur ^ 1][64 + sr][sc] = b10;
      *(v8s*)&Bs[cur ^ 1][64 + sr][sc + 8] = b11;
      __syncthreads();
    }
  }

  if (!vmode) {
    u16* outp = (op == 0) ? Qb : Kb;
    // 0.125 (d^-0.5) * log2(e) folded so attn can use exp2 directly
    const float osc = (op == 0) ? 0.18033688011112042f : 1.0f;
    float bv4[4];
    for (int nt = 0; nt < 4; ++nt) bv4[nt] = bias[n0 + wc * 64 + nt * 16 + l16];
    for (int i = 0; i < 4; ++i) {
      const int rowb = m0 + wr * 64 + i * 16 + quad * 4;
      for (int r = 0; r < 4; ++r) {
        const int row = rowb + r;
        if (row >= kRows) continue;
        for (int nt = 0; nt < 4; ++nt) {
          const int col = n0 + wc * 64 + nt * 16 + l16;
          outp[(size_t)row * kC + col] = f2b((acc[i][nt][r] + bv4[nt]) * osc);
        }
      }
    }
  } else {
    u16* Vt = (op == 2) ? Vt1 : Vt2;
    for (int nt = 0; nt < 4; ++nt) {
      const int t = n0 + wc * 64 + nt * 16 + l16;  // token
      if (t >= kRows) continue;
      const int bb = t / kN1, mm = t - bb * kN1;
      for (int i = 0; i < 4; ++i) {
        const int colb = m0 + wr * 64 + i * 16 + quad * 4;
        for (int r = 0; r < 4; ++r) {
          const int col = colb + r;
          const int hh = col >> 6, d = col & 63;
          Vt[((size_t)(bb * kH + hh) * 64 + d) * kPld + mm] =
              f2b(acc[i][nt][r] + bias[col]);
        }
      }
    }
  }
}

// ---- fused flash attention: 8 FULL k-tiles + exact k=512 epilogue.
// Double-buffered Ks/Vs: ONE barrier per k-tile (loads issued at iter start,
// reg->LDS writes after compute). Ps is wave-private (no barrier needed).
// Blocks with q0==512 take a slim GEVM path. setprio(1) wraps MFMA clusters.
__global__ __launch_bounds__(256) void attn_fused(const u16* __restrict__ Qb,
                                                  const u16* __restrict__ Kb,
                                                  const u16* __restrict__ Vt1,
                                                  const u16* __restrict__ Vt2,
                                                  u16* __restrict__ PRE) {
  __shared__ __align__(16) u16 Ks[2][64][72];
  __shared__ __align__(16) u16 Vs[2][128][72];
  __shared__ __align__(16) u16 Ps[4][16][72];
  const int bid = blockIdx.x;
  const int xcd = bid & 7;
  const int t6 = bid >> 3;           // 0..53
  const int bh = xcd * 6 + (t6 % 6); // 0..47
  const int q0 = (t6 / 6) * 64;      // 9 q-tiles
  const int b = bh / kH, hh = bh - b * kH;
  const int tid = threadIdx.x;
  const int w = tid >> 6, lane = tid & 63, l16 = lane & 15, quad = lane >> 4;

  if (q0 == 512) {  // ---- slim path: only q-row 512 is valid ----
    float* Pp = (float*)&Ks[0][0][0];    // 513 floats
    float* Rd = (float*)&Vs[0][0][0];    // 256 floats
    float* wred = (float*)&Ps[0][0][0];  // 4 floats
    v8s q8[8];
    const u16* qs = Qb + ((size_t)(b * kN1 + 512)) * kC + hh * 64;
    for (int c = 0; c < 8; ++c) q8[c] = *(const v8s*)(qs + c * 8);
    for (int k = tid; k < kN1; k += 256) {
      const u16* kr = Kb + ((size_t)(b * kN1 + k)) * kC + hh * 64;
      float s = 0.f;
      for (int c = 0; c < 8; ++c) {
        const v8s kv = *(const v8s*)(kr + c * 8);
        for (int jj = 0; jj < 8; ++jj)
          s += b2f((u16)q8[c][jj]) * b2f((u16)kv[jj]);
      }
      Pp[k] = EXP2F(s);
    }
    __syncthreads();
    float part = 0.f;
    for (int k = tid; k < kN1; k += 256) part += Pp[k];
    for (int o = 1; o < 64; o <<= 1) part += __shfl_xor(part, o);
    if (lane == 0) wred[w] = part;
    __syncthreads();
    const float rinv = 1.f / (wred[0] + wred[1] + wred[2] + wred[3]);
    const int d = tid & 127, half = tid >> 7;
    const u16* vrow = (d < 64) ? (Vt1 + ((size_t)bh * 64 + d) * kPld)
                               : (Vt2 + ((size_t)bh * 64 + (d - 64)) * kPld);
    float acc = 0.f;
    const int kb0 = half * 256;
    for (int k8 = 0; k8 < 256; k8 += 8) {
      const v8s vv = *(const v8s*)(vrow + kb0 + k8);
      for (int jj = 0; jj < 8; ++jj)
        acc += Pp[kb0 + k8 + jj] * b2f((u16)vv[jj]);
    }
    if (half) acc += Pp[512] * b2f(vrow[512]);
    Rd[tid] = acc;
    __syncthreads();
    if (tid < 128) {
      const float o = (Rd[tid] + Rd[tid + 128]) * rinv;
      const int row = b * 1026 + ((d < 64) ? 512 : (kN1 + 512));
      const int col = hh * 64 + (d & 63);
      PRE[(size_t)row * kC + col] = f2b(o);
    }
    return;
  }

  v8s aq0, aq1;
  {  // Q fragments straight from global (each wave reads only its 16 rows)
    const int qr = q0 + w * 16 + l16;  // q0 <= 448 here: qr <= 511
    const u16* qs = Qb + ((size_t)(b * kN1 + qr)) * kC + hh * 64 + quad * 8;
    aq0 = *(const v8s*)qs;
    aq1 = *(const v8s*)(qs + 32);
  }
  const int ksr = tid >> 2, ksc = (tid & 3) * 16;
  const int vd = tid >> 1, vc = (tid & 1) * 32;
  const u16* kbase = Kb + (size_t)b * kN1 * kC + hh * 64 + ksc;
  const u16* vbase = ((vd < 64) ? (Vt1 + ((size_t)bh * 64 + vd) * kPld)
                                : (Vt2 + ((size_t)bh * 64 + (vd - 64)) * kPld)) +
                     vc;
  v8s kr0, kr1, vr0, vr1, vr2, vr3;
  {  // load tile 0 and stage into buf 0
    const u16* s = kbase + (size_t)ksr * kC;
    kr0 = *(const v8s*)s;
    kr1 = *(const v8s*)(s + 8);
    vr0 = *(const v8s*)(vbase);
    vr1 = *(const v8s*)(vbase + 8);
    vr2 = *(const v8s*)(vbase + 16);
    vr3 = *(const v8s*)(vbase + 24);
    *(v8s*)&Ks[0][ksr][ksc] = kr0;
    *(v8s*)&Ks[0][ksr][ksc + 8] = kr1;
    *(v8s*)&Vs[0][vd][vc] = vr0;
    *(v8s*)&Vs[0][vd][vc + 8] = vr1;
    *(v8s*)&Vs[0][vd][vc + 16] = vr2;
    *(v8s*)&Vs[0][vd][vc + 24] = vr3;
  }
  __syncthreads();

  float lsum[4] = {0.f, 0.f, 0.f, 0.f};
  v4f Oacc[8];
  const v4f z4 = {0.f, 0.f, 0.f, 0.f};
  for (int n = 0; n < 8; ++n) Oacc[n] = z4;

  for (int kt = 0; kt < 8; ++kt) {
    const int cur = kt & 1;
    if (kt < 7) {  // issue loads for kt+1 at iter start; hide under compute
      const int k0n = kt * 64 + 64;
      const u16* s = kbase + (size_t)(k0n + ksr) * kC;  // rows <= 511
      kr0 = *(const v8s*)s;
      kr1 = *(const v8s*)(s + 8);
      const u16* t = vbase + k0n;
      vr0 = *(const v8s*)t;
      vr1 = *(const v8s*)(t + 8);
      vr2 = *(const v8s*)(t + 16);
      vr3 = *(const v8s*)(t + 24);
    }
    v4f sacc[4];
    for (int nt = 0; nt < 4; ++nt) sacc[nt] = z4;
    __builtin_amdgcn_s_setprio(1);
    for (int nt = 0; nt < 4; ++nt) {
      const v8s bk0 = *(const v8s*)&Ks[cur][nt * 16 + l16][quad * 8];
      sacc[nt] = __builtin_amdgcn_mfma_f32_16x16x32_bf16(aq0, bk0, sacc[nt], 0, 0, 0);
      const v8s bk1 = *(const v8s*)&Ks[cur][nt * 16 + l16][32 + quad * 8];
      sacc[nt] = __builtin_amdgcn_mfma_f32_16x16x32_bf16(aq1, bk1, sacc[nt], 0, 0, 0);
    }
    __builtin_amdgcn_s_setprio(0);
    for (int r = 0; r < 4; ++r) {  // all 8 tiles fully valid: no masking
      float ps = 0.f;
      for (int nt = 0; nt < 4; ++nt) {
        const float p = EXP2F(sacc[nt][r]);
        ps += p;
        Ps[w][quad * 4 + r][nt * 16 + l16] = f2b(p);
      }
      lsum[r] += ps;
    }
    __builtin_amdgcn_s_setprio(1);
    for (int kc = 0; kc < 2; ++kc) {
      const v8s ap = *(const v8s*)&Ps[w][l16][kc * 32 + quad * 8];
      for (int n = 0; n < 8; ++n) {
        const v8s bv = *(const v8s*)&Vs[cur][n * 16 + l16][kc * 32 + quad * 8];
        Oacc[n] = __builtin_amdgcn_mfma_f32_16x16x32_bf16(ap, bv, Oacc[n], 0, 0, 0);
      }
    }
    __builtin_amdgcn_s_setprio(0);
    if (kt < 7) {  // stage kt+1 into the other buffer; ONE barrier per iter
      *(v8s*)&Ks[cur ^ 1][ksr][ksc] = kr0;
      *(v8s*)&Ks[cur ^ 1][ksr][ksc + 8] = kr1;
      *(v8s*)&Vs[cur ^ 1][vd][vc] = vr0;
      *(v8s*)&Vs[cur ^ 1][vd][vc + 8] = vr1;
      *(v8s*)&Vs[cur ^ 1][vd][vc + 16] = vr2;
      *(v8s*)&Vs[cur ^ 1][vd][vc + 24] = vr3;
      __syncthreads();
    }
  }

  {  // ---- exact k = 512 column ----
    const u16* k512 = Kb + ((size_t)(b * kN1 + 512)) * kC + hh * 64 + quad * 8;
    const v8s kv0 = *(const v8s*)k512;
    const v8s kv1 = *(const v8s*)(k512 + 32);
    float part = 0.f;
    for (int jj = 0; jj < 8; ++jj) {
      part += b2f((u16)aq0[jj]) * b2f((u16)kv0[jj]);
      part += b2f((u16)aq1[jj]) * b2f((u16)kv1[jj]);
    }
    part += __shfl_xor(part, 16);
    part += __shfl_xor(part, 32);  // all lanes: full dot for row w*16+l16
    const float p512 = EXP2F(part);
    float pb[4];
    for (int r = 0; r < 4; ++r) pb[r] = __shfl(p512, quad * 4 + r);
    // each of the 16 l16-lanes adds pb; the final xor-reduce over l16 sums
    // them 16x -> scale by 1/16 so p512 is counted exactly once per row.
    for (int r = 0; r < 4; ++r) lsum[r] += pb[r] * 0.0625f;
    for (int n = 0; n < 8; ++n) {
      const int d = (n & 3) * 16 + l16;
      const u16* vp = (n < 4) ? (Vt1 + ((size_t)bh * 64 + d) * kPld + 512)
                              : (Vt2 + ((size_t)bh * 64 + d) * kPld + 512);
      const float vv = b2f(*vp);
      for (int r = 0; r < 4; ++r) Oacc[n][r] += pb[r] * vv;
    }
  }

  float rinv[4];
  for (int r = 0; r < 4; ++r) {
    float s = lsum[r];
    for (int o = 1; o <= 8; o <<= 1) s += __shfl_xor(s, o);
    rinv[r] = 1.f / s;
  }
  for (int n = 0; n < 8; ++n) {
    const int col = hh * 64 + (n & 3) * 16 + l16;
    const int rbase = b * 1026 + ((n < 4) ? 0 : kN1);
    for (int r = 0; r < 4; ++r) {
      const int q = q0 + w * 16 + quad * 4 + r;
      PRE[(size_t)(rbase + q) * kC + col] = f2b(Oacc[n][r] * rinv[r]);
    }
  }
}

// ---- OUT = PRE @ Wo + bo (fp32 out). Double-buffered LDS, ONE barrier
// per k-tile (6 tiles of 64 over kC=384); hoisted row pointers; clamped
// tail rows (discarded at write). 128x128 tile, grid (65,3): R8's 128x64
// split regressed (+1.9us — doubled A-staging traffic beat the CU-idle win).
__global__ __launch_bounds__(256) void out_mfma(const u16* __restrict__ PRE,
                                                const u16* __restrict__ Wot,
                                                const float* __restrict__ bo,
                                                float* __restrict__ OUT) {
  __shared__ __align__(16) u16 As[2][128][72];
  __shared__ __align__(16) u16 Bs[2][128][72];
  const int m0 = blockIdx.x * 128, n0 = blockIdx.y * 128;
  const int tid = threadIdx.x;
  const int lane = tid & 63, l16 = lane & 15, quad = lane >> 4;
  const int wv = tid >> 6, wr = wv >> 1, wc = wv & 1;
  const int sr = tid >> 2, sc = (tid & 3) * 16;
  v4f acc[4][4];
  const v4f z4 = {0.f, 0.f, 0.f, 0.f};
  for (int i = 0; i < 4; ++i)
    for (int n = 0; n < 4; ++n) acc[i][n] = z4;

  int rA0 = m0 + sr;       if (rA0 >= kRows2) rA0 = kRows2 - 1;
  int rA1 = m0 + 64 + sr;  if (rA1 >= kRows2) rA1 = kRows2 - 1;
  const u16* pA0 = PRE + (size_t)rA0 * kC + sc;
  const u16* pA1 = PRE + (size_t)rA1 * kC + sc;
  const u16* pB0 = Wot + (size_t)(n0 + sr) * kC + sc;
  const u16* pB1 = Wot + (size_t)(n0 + 64 + sr) * kC + sc;

  v8s a00 = *(const v8s*)pA0, a01 = *(const v8s*)(pA0 + 8);
  v8s a10 = *(const v8s*)pA1, a11 = *(const v8s*)(pA1 + 8);
  v8s b00 = *(const v8s*)pB0, b01 = *(const v8s*)(pB0 + 8);
  v8s b10 = *(const v8s*)pB1, b11 = *(const v8s*)(pB1 + 8);
  *(v8s*)&As[0][sr][sc] = a00;
  *(v8s*)&As[0][sr][sc + 8] = a01;
  *(v8s*)&As[0][64 + sr][sc] = a10;
  *(v8s*)&As[0][64 + sr][sc + 8] = a11;
  *(v8s*)&Bs[0][sr][sc] = b00;
  *(v8s*)&Bs[0][sr][sc + 8] = b01;
  *(v8s*)&Bs[0][64 + sr][sc] = b10;
  *(v8s*)&Bs[0][64 + sr][sc + 8] = b11;
  __syncthreads();

  for (int it = 0; it < 6; ++it) {
    const int cur = it & 1;
    if (it < 5) {
      pA0 += 64; pA1 += 64; pB0 += 64; pB1 += 64;
      a00 = *(const v8s*)pA0; a01 = *(const v8s*)(pA0 + 8);
      a10 = *(const v8s*)pA1; a11 = *(const v8s*)(pA1 + 8);
      b00 = *(const v8s*)pB0; b01 = *(const v8s*)(pB0 + 8);
      b10 = *(const v8s*)pB1; b11 = *(const v8s*)(pB1 + 8);
    }
    for (int ks = 0; ks < 2; ++ks) {
      v8s af[4], bfr[4];
      for (int i = 0; i < 4; ++i)
        af[i] = *(const v8s*)&As[cur][wr * 64 + i * 16 + l16][ks * 32 + quad * 8];
      for (int n = 0; n < 4; ++n)
        bfr[n] = *(const v8s*)&Bs[cur][wc * 64 + n * 16 + l16][ks * 32 + quad * 8];
      for (int i = 0; i < 4; ++i)
        for (int n = 0; n < 4; ++n)
          acc[i][n] = __builtin_amdgcn_mfma_f32_16x16x32_bf16(af[i], bfr[n],
                                                              acc[i][n], 0, 0, 0);
    }
    if (it < 5) {
      *(v8s*)&As[cur ^ 1][sr][sc] = a00;
      *(v8s*)&As[cur ^ 1][sr][sc + 8] = a01;
      *(v8s*)&As[cur ^ 1][64 + sr][sc] = a10;
      *(v8s*)&As[cur ^ 1][64 + sr][sc + 8] = a11;
      *(v8s*)&Bs[cur ^ 1][sr][sc] = b00;
      *(v8s*)&Bs[cur ^ 1][sr][sc + 8] = b01;
      *(v8s*)&Bs[cur ^ 1][64 + sr][sc] = b10;
      *(v8s*)&Bs[cur ^ 1][64 + sr][sc + 8] = b11;
      __syncthreads();
    }
  }
  float bv4[4];
  for (int nt = 0; nt < 4; ++nt) bv4[nt] = bo[n0 + wc * 64 + nt * 16 + l16];
  for (int i = 0; i < 4; ++i) {
    const int rowb = m0 + wr * 64 + i * 16 + quad * 4;
    for (int r = 0; r < 4; ++r) {
      const int row = rowb + r;
      if (row >= kRows2) continue;
      for (int nt = 0; nt < 4; ++nt) {
        const int col = n0 + wc * 64 + nt * 16 + l16;
        OUT[(size_t)row * kC + col] = acc[i][nt][r] + bv4[nt];
      }
    }
  }
}

extern "C" void kernel_launch(void* const* d_in, const int* in_sizes, int n_in,
                              void* d_out, int out_size, void* d_ws,
                              size_t ws_size, hipStream_t stream) {
  const float* x = (const float*)d_in[0];
  const float* Wq1 = (const float*)d_in[1];
  const float* bq1 = (const float*)d_in[2];
  const float* Wq2 = (const float*)d_in[3];
  const float* bq2 = (const float*)d_in[4];
  const float* Wk1 = (const float*)d_in[5];
  const float* bk1 = (const float*)d_in[6];
  const float* Wk2 = (const float*)d_in[7];
  const float* bk2 = (const float*)d_in[8];
  const float* Wv1 = (const float*)d_in[9];
  const float* bv1 = (const float*)d_in[10];
  const float* Wv2 = (const float*)d_in[11];
  const float* bv2 = (const float*)d_in[12];
  const float* Wo = (const float*)d_in[13];
  const float* bo = (const float*)d_in[14];
  const float* wts = (const float*)d_in[15];
  const float* gum = (const float*)d_in[16];
  (void)Wo;

  u16* Wqt = (u16*)d_ws;                         // 147456 elems each
  u16* Wkt = Wqt + 147456;
  u16* Wv1t = Wkt + 147456;
  u16* Wv2t = Wv1t + 147456;
  u16* Wot = Wv2t + 147456;
  u16* Qb = Wot + 147456;                        // 4104*384
  u16* Kb = Qb + (size_t)kRows * kC;             // 4104*384
  u16* Vt1 = Kb + (size_t)kRows * kC;            // 48*64*576
  u16* Vt2 = Vt1 + (size_t)kBH * 64 * kPld;      // 48*64*576
  u16* PRE = Vt2 + (size_t)kBH * 64 * kPld;      // 8208*384
  u16* XB = PRE + (size_t)kRows2 * kC;           // 8208*384 bf16 x

  prep_w<<<dim3(1490), 256, 0, stream>>>(Wq1, Wq2, Wk1, Wk2, Wv1, Wv2, Wo, x,
                                         wts, gum, Wqt, Wkt, Wv1t, Wv2t, Wot,
                                         XB);
  qkv_mfma<<<dim3(400), 256, 0, stream>>>(
      XB, Wqt, Wkt, Wv1t, Wv2t, bq1, bq2, bk1, bk2, bv1, bv2, wts, gum, Qb, Kb,
      Vt1, Vt2);
  attn_fused<<<dim3(432), 256, 0, stream>>>(Qb, Kb, Vt1, Vt2, PRE);
  out_mfma<<<dim3(65, 3), 256, 0, stream>>>(PRE, Wot, bo, (float*)d_out);
}